// Round 14
// baseline (132.854 us; speedup 1.0000x reference)
//
#include <hip/hip_runtime.h>
#include <hip/hip_bf16.h>

#define BB 8
#define NN 512
#define AH 12
#define DIN 768
#define EE 64
#define MM (BB*NN)          // 4096
#define YY (BB*AH)          // 96
#define LEAKY 0.2f

typedef unsigned short u16;
typedef unsigned int u32;
typedef __attribute__((ext_vector_type(8))) short short8;
typedef __attribute__((ext_vector_type(4))) float f32x4;
typedef __attribute__((ext_vector_type(4))) u32 u32x4;

// float -> bf16 RNE
static __device__ __forceinline__ u16 f2bf(float f) {
    u32 u = __builtin_bit_cast(u32, f);
    u32 r = (u + 0x7FFFu + ((u >> 16) & 1u)) >> 16;
    return (u16)r;
}
static __device__ __forceinline__ u32 pk2(float a, float b) {
    return (u32)f2bf(a) | ((u32)f2bf(b) << 16);
}
// truncation pack (p >= 0): used only for P (rel err <= 2^-8)
static __device__ __forceinline__ u32 pk2t(float a, float b) {
    return (__builtin_bit_cast(u32, a) >> 16) | (__builtin_bit_cast(u32, b) & 0xFFFF0000u);
}
static __device__ __forceinline__ float ftanh(float x) {
    x = fminf(fmaxf(x, -15.f), 15.f);
    return 1.f - 2.f / (__expf(2.f * x) + 1.f);
}
static __device__ __forceinline__ float sigm(float z) {
    z = fminf(fmaxf(z, -80.f), 80.f);
    return 1.f / (1.f + __expf(-z));
}
// async global->LDS, 16B per lane
static __device__ __forceinline__ void gl_lds16(const u16* g, u16* l) {
    __builtin_amdgcn_global_load_lds((const __attribute__((address_space(1))) unsigned int*)g,
                                     (__attribute__((address_space(3))) unsigned int*)l,
                                     16, 0, 0);
}

// ---------------------------------------------------------------------------
// Hardware C/D-layout probe (validated rounds 6-13).
// ---------------------------------------------------------------------------
static __device__ __forceinline__ void mfma_probe(int lane, int* prow, int* pcol) {
    int q = lane >> 4, x = lane & 15;
    short8 af, bf;
#pragma unroll
    for (int j = 0; j < 8; j++) {
        int k = q * 8 + j;
        af[j] = (short)f2bf((k < 16) ? (float)(x * 16 + k) : 0.f);
        bf[j] = (short)f2bf((k == x) ? 1.f : 0.f);
    }
    f32x4 d = {};
    d = __builtin_amdgcn_mfma_f32_16x16x32_bf16(af, bf, d, 0, 0, 0);
#pragma unroll
    for (int r = 0; r < 4; r++) {
        int v = (int)(d[r] + 0.5f);
        prow[r] = v >> 4;
        pcol[r] = v & 15;
    }
}

// ---------------------------------------------------------------------------
// Prep: pack_adj (blocks 0..1023) + bf16 conversions (verified).
// ---------------------------------------------------------------------------
#define N_FEAT (MM*DIN)            // 3145728
#define N_W    (AH*DIN*EE)         // 589824
#define PACK_BLOCKS (MM/4)         // 1024
#define CONV_BLOCKS ((N_FEAT + 2*N_W)/256)  // 16896
__global__ __launch_bounds__(256) void prep_kernel(const int* __restrict__ adj,
                                                   const float* __restrict__ feat,
                                                   const float* __restrict__ W,
                                                   const float* __restrict__ Hw,
                                                   u32* __restrict__ maskbuf,
                                                   u16* __restrict__ featb,
                                                   u16* __restrict__ Wt,
                                                   u16* __restrict__ Hwb) {
    int blk = blockIdx.x, t = threadIdx.x;
    if (blk < PACK_BLOCKS) {
        int w = t >> 6, ln = t & 63;
        int row = blk * 4 + w;
        const int* ar = adj + (size_t)row * NN;
#pragma unroll
        for (int it = 0; it < 8; it++) {
            unsigned long long bal = __ballot(ar[it * 64 + ln] != 0);
            if (ln == 0) {
                maskbuf[row * 16 + it * 2]     = (u32)bal;
                maskbuf[row * 16 + it * 2 + 1] = (u32)(bal >> 32);
            }
        }
        return;
    }
    int i = (blk - PACK_BLOCKS) * 256 + t;
    if (i < N_FEAT) { featb[i] = f2bf(feat[i]); return; }
    int i2 = i - N_FEAT;
    if (i2 < N_W) {
        int a = i2 / (DIN * EE), rem = i2 % (DIN * EE);
        int e = rem / DIN, d = rem % DIN;
        Wt[i2] = f2bf(W[a * (DIN * EE) + d * EE + e]);
        return;
    }
    int i3 = i2 - N_W;
    Hwb[i3] = f2bf(Hw[i3]);
}

// ---------------------------------------------------------------------------
// K-loop core, 128-thread variant: 32x64 C tile, BK=64, global_load_lds
// staging, XOR k-swizzle, probe-indexed C->LDS. Same fragment/staging
// conventions as the verified 256-thread core (rows ≡ mod 8 across calls,
// so the per-thread skoff is valid for every 16-row call group).
// Wave w supplies A rows w*16+x; both waves read all 64 B rows.
// ---------------------------------------------------------------------------
#define GEMM_CORE_32(Abase, Bbase)                                            \
    int xr = x & 7;                                                           \
    int srow = t >> 3;                                                        \
    int skoff = ((t & 7) ^ (srow & 7)) * 8;                                   \
    const u16* Agp = (Abase) + srow * DIN + skoff;                            \
    const u16* Bgp = (Bbase) + srow * DIN + skoff;                            \
    u16* Asw = As + w * 512;                                                  \
    u16* Bsw = Bs + w * 512;                                                  \
    const u16* ApA = As + (w * 16 + x) * 64;                                  \
    const u16* ApB = Bs + x * 64;                                             \
    f32x4 accv[4] = {};                                                       \
    for (int k0 = 0; k0 < DIN; k0 += 64) {                                    \
        gl_lds16(Agp + k0, Asw);                                              \
        gl_lds16(Agp + 16 * DIN + k0, Asw + 1024);                            \
        gl_lds16(Bgp + k0, Bsw);                                              \
        gl_lds16(Bgp + 16 * DIN + k0, Bsw + 1024);                            \
        gl_lds16(Bgp + 32 * DIN + k0, Bsw + 2048);                            \
        gl_lds16(Bgp + 48 * DIN + k0, Bsw + 3072);                            \
        __syncthreads();                                                      \
        _Pragma("unroll")                                                     \
        for (int kk = 0; kk < 2; kk++) {                                      \
            int c8 = ((q + kk * 4) ^ xr) * 8;                                 \
            short8 a0 = *(const short8*)(ApA + c8);                           \
            short8 b0 = *(const short8*)(ApB + c8);                           \
            short8 b1 = *(const short8*)(ApB + 16 * 64 + c8);                 \
            short8 b2 = *(const short8*)(ApB + 32 * 64 + c8);                 \
            short8 b3 = *(const short8*)(ApB + 48 * 64 + c8);                 \
            accv[0] = __builtin_amdgcn_mfma_f32_16x16x32_bf16(a0, b0, accv[0], 0, 0, 0); \
            accv[1] = __builtin_amdgcn_mfma_f32_16x16x32_bf16(a0, b1, accv[1], 0, 0, 0); \
            accv[2] = __builtin_amdgcn_mfma_f32_16x16x32_bf16(a0, b2, accv[2], 0, 0, 0); \
            accv[3] = __builtin_amdgcn_mfma_f32_16x16x32_bf16(a0, b3, accv[3], 0, 0, 0); \
        }                                                                     \
        __syncthreads();                                                      \
    }                                                                         \
    int prowc[4], pcolc[4];                                                   \
    mfma_probe(lane, prowc, pcolc);                                           \
    _Pragma("unroll")                                                         \
    for (int nt = 0; nt < 4; nt++)                                            \
        _Pragma("unroll")                                                     \
        for (int r = 0; r < 4; r++)                                           \
            cs[w * 16 + prowc[r]][nt * 16 + pcolc[r]] = accv[nt][r];          \
    __syncthreads();

// ---------------------------------------------------------------------------
// GEMM h: 32 nodes x 64 e (one head), 128 threads, grid (128, 12) = 1536.
// Epilogue: bf16 hT3 [y][kc][e][8] + factored exp pairs.
// ---------------------------------------------------------------------------
__global__ __launch_bounds__(128) void gemm_h_kernel(const u16* __restrict__ featb,
                                                     const u16* __restrict__ Wt,
                                                     const float* __restrict__ wsrc,
                                                     const float* __restrict__ wdst,
                                                     u16* __restrict__ hT,
                                                     float2* __restrict__ Spair,
                                                     float2* __restrict__ Dpair) {
    __shared__ u16 As[32 * 64];
    __shared__ u16 Bs[64 * 64];
    __shared__ alignas(16) float cs[32][68];
    int t = threadIdx.x, w = t >> 6, lane = t & 63, q = lane >> 4, x = lane & 15;
    int m0 = blockIdx.x * 32, a = blockIdx.y;

    GEMM_CORE_32(featb + (size_t)m0 * DIN, Wt + (size_t)a * EE * DIN)

    int b = m0 >> 9;
    int y = b * AH + a;
    int nbase = m0 & 511;
    // (a) hT3 [y][kc][e][8]
    {
        int kcb = nbase >> 3;
#pragma unroll
        for (int i = 0; i < 2; i++) {
            int idx = i * 128 + t;
            int kcl = idx >> 6, e = idx & 63;
            int r0 = kcl * 8;
            u32x4 wv = { pk2(cs[r0 + 0][e], cs[r0 + 1][e]),
                         pk2(cs[r0 + 2][e], cs[r0 + 3][e]),
                         pk2(cs[r0 + 4][e], cs[r0 + 5][e]),
                         pk2(cs[r0 + 6][e], cs[r0 + 7][e]) };
            *(u32x4*)&hT[((((size_t)y << 6) + kcb + kcl) << 6 | e) * 8] = wv;
        }
    }
    // (b) factored exp pairs: r = t>>2 covers 32 rows, 4 threads/row
    {
        int r = t >> 2, cg = t & 3;
        float s = 0.f, d = 0.f;
#pragma unroll
        for (int i = 0; i < 16; i++) {
            int e2 = cg * 16 + i;
            float th = ftanh(cs[r][e2]);
            s += th * wsrc[a * EE + e2];
            d += th * wdst[a * EE + e2];
        }
        s += __shfl_xor(s, 1); s += __shfl_xor(s, 2);
        d += __shfl_xor(d, 1); d += __shfl_xor(d, 2);
        if (cg == 0) {
            s = fminf(fmaxf(s, -40.f), 40.f);
            d = fminf(fmaxf(d, -40.f), 40.f);
            Spair[y * NN + nbase + r] = make_float2(__expf(s), __expf(0.2f * s));
            Dpair[y * NN + nbase + r] = make_float2(__expf(d), __expf(0.2f * d));
        }
    }
}

// ---------------------------------------------------------------------------
// Attention + fused gate GEMM, 128 threads, 32 q-rows, grid (16, 96) = 1536.
// Phase 1: gate 32x64 tile -> sigmoid in 16 VGPRs. Phase 2: PV via MFMA
// (factored exp, on-the-fly row sum, coalesced hT3 B-loads).
// ---------------------------------------------------------------------------
__global__ __launch_bounds__(128) void attn_kernel(const u16* __restrict__ hT,
                                                   const float2* __restrict__ Spair,
                                                   const float2* __restrict__ Dpair,
                                                   const u32* __restrict__ maskbuf,
                                                   const float* __restrict__ bias,
                                                   const u16* __restrict__ featb,
                                                   const u16* __restrict__ Hwb,
                                                   const float* __restrict__ Hb,
                                                   const float* __restrict__ feat,
                                                   float* __restrict__ out) {
    __shared__ union {
        struct { u16 A[32 * 64]; u16 B[64 * 64]; } st;   // 12 KB gate staging
        struct { float2 sd2[NN]; u32 smask[32][17]; } pv; // 6.2 KB
    } ushr;
    __shared__ alignas(16) float cs[32][68];
    __shared__ float silv[32];

    int t = threadIdx.x;
    int y = blockIdx.y, bb = y / AH, a = y % AH;
    int i0 = blockIdx.x * 32;
    int w = t >> 6, lane = t & 63, q = lane >> 4, x = lane & 15;

    // ---- phase 1: gate GEMM tile -> sigmoid in registers ----
    float4 g4[4];
    {
        u16* As = ushr.st.A;
        u16* Bs = ushr.st.B;
        GEMM_CORE_32(featb + ((size_t)(bb << 9) + i0) * DIN, Hwb + (size_t)(a * EE) * DIN)
        float4 hb = *(const float4*)&Hb[a * EE + (t & 15) * 4];
#pragma unroll
        for (int p = 0; p < 4; p++) {
            int ml = p * 8 + (t >> 4), c4 = (t & 15) * 4;
            float4 v4 = *(const float4*)&cs[ml][c4];
            g4[p].x = sigm(v4.x + hb.x);
            g4[p].y = sigm(v4.y + hb.y);
            g4[p].z = sigm(v4.z + hb.z);
            g4[p].w = sigm(v4.w + hb.w);
        }
    }

    // ---- load PV working set (staging region is dead; union reuse) ----
    float2* sd2 = ushr.pv.sd2;
    u32 (*smask)[17] = ushr.pv.smask;
#pragma unroll
    for (int p = 0; p < 4; p++) sd2[p * 128 + t] = Dpair[y * NN + p * 128 + t];
#pragma unroll
    for (int p = 0; p < 4; p++) {
        int idx = p * 128 + t, r = idx >> 4, c = idx & 15;
        smask[r][c] = maskbuf[((bb << 9) + i0 + r) * 16 + c];
    }
    __syncthreads();   // also orders phase-1 cs reads before PV cs writes

    // ---- phase 2: PV via MFMA ----
    int rowl = w * 16 + x;
    float2 se = Spair[y * NN + i0 + rowl];
    float es1 = se.x, es2 = se.y;

    u32 anym = 0;
#pragma unroll
    for (int c = 0; c < 16; c++) anym |= smask[rowl][c];
    int uni = (anym == 0);

    const u16* hTy = hT + ((size_t)y << 12) * 8;     // y * 64 * 64 * 8
    f32x4 acc[4] = {};
    float lsum = 0.f;

#pragma unroll 2
    for (int k0 = 0; k0 < NN; k0 += 32) {
        u32 mb = smask[rowl][k0 >> 5] >> (q * 8);
        float pv[8];
#pragma unroll
        for (int j = 0; j < 8; j++) {
            float2 dp = sd2[k0 + q * 8 + j];
            float m1 = es1 * dp.x;
            float m2 = es2 * dp.y;
            float p = (m1 >= 1.f) ? m1 : m2;    // exp(leaky(s+d))
            p = ((mb >> j) & 1) ? p : 0.f;
            p = uni ? 1.0f : p;
            lsum += p;
            pv[j] = p;
        }
        short8 af = __builtin_bit_cast(short8, (u32x4){
            pk2t(pv[0], pv[1]), pk2t(pv[2], pv[3]),
            pk2t(pv[4], pv[5]), pk2t(pv[6], pv[7])});
        const u16* hp = hTy + ((((k0 >> 3) + q) << 6) + x) * 8;
        short8 b0 = *(const short8*)(hp);
        short8 b1 = *(const short8*)(hp + 16 * 8);
        short8 b2 = *(const short8*)(hp + 32 * 8);
        short8 b3 = *(const short8*)(hp + 48 * 8);
        acc[0] = __builtin_amdgcn_mfma_f32_16x16x32_bf16(af, b0, acc[0], 0, 0, 0);
        acc[1] = __builtin_amdgcn_mfma_f32_16x16x32_bf16(af, b1, acc[1], 0, 0, 0);
        acc[2] = __builtin_amdgcn_mfma_f32_16x16x32_bf16(af, b2, acc[2], 0, 0, 0);
        acc[3] = __builtin_amdgcn_mfma_f32_16x16x32_bf16(af, b3, acc[3], 0, 0, 0);
    }

    lsum += __shfl_xor(lsum, 16);
    lsum += __shfl_xor(lsum, 32);
    if (q == 0) silv[rowl] = 1.f / fmaxf(lsum, 1e-30f);

    int prow[4], pcol[4];
    mfma_probe(lane, prow, pcol);
#pragma unroll
    for (int nt = 0; nt < 4; nt++)
#pragma unroll
        for (int r = 0; r < 4; r++)
            cs[w * 16 + prow[r]][nt * 16 + pcol[r]] = acc[nt][r];
    __syncthreads();

    // ---- epilogue: normalize, +bias, elu, gate blend ----
    float4 b4 = *(const float4*)&bias[(t & 15) * 4];
#pragma unroll
    for (int p = 0; p < 4; p++) {
        int nl = p * 8 + (t >> 4), e4 = (t & 15) * 4;
        float il = silv[nl];
        float4 c4 = *(const float4*)&cs[nl][e4];
        size_t base = ((size_t)(bb << 9) + i0 + nl) * DIN + a * EE + e4;
        float4 f4 = *(const float4*)&feat[base];
        float4 g = g4[p];
        float4 o;
        float v, e;
        v = c4.x * il + b4.x; e = v > 0.f ? v : __expf(v) - 1.f; o.x = g.x * e + (1.f - g.x) * f4.x;
        v = c4.y * il + b4.y; e = v > 0.f ? v : __expf(v) - 1.f; o.y = g.y * e + (1.f - g.y) * f4.y;
        v = c4.z * il + b4.z; e = v > 0.f ? v : __expf(v) - 1.f; o.z = g.z * e + (1.f - g.z) * f4.z;
        v = c4.w * il + b4.w; e = v > 0.f ? v : __expf(v) - 1.f; o.w = g.w * e + (1.f - g.w) * f4.w;
        *(float4*)&out[base] = o;
    }
}

// ---------------------------------------------------------------------------
extern "C" void kernel_launch(void* const* d_in, const int* in_sizes, int n_in,
                              void* d_out, int out_size, void* d_ws, size_t ws_size,
                              hipStream_t stream) {
    const float* feat  = (const float*)d_in[0];
    const int*   adj   = (const int*)  d_in[1];
    const float* W     = (const float*)d_in[2];
    const float* bvec  = (const float*)d_in[3];
    const float* wsrc  = (const float*)d_in[4];
    const float* wdst  = (const float*)d_in[5];
    const float* Hw    = (const float*)d_in[6];
    const float* Hb    = (const float*)d_in[7];
    float* out = (float*)d_out;

    char* ws = (char*)d_ws;
    u16*    featb   = (u16*)(ws);                       // 6,291,456 B
    u16*    Wt      = (u16*)(ws + 6291456);             // 1,179,648 B
    u16*    Hwb     = (u16*)(ws + 7471104);             // 1,179,648 B
    u16*    hT      = (u16*)(ws + 8650752);             // 6,291,456 B
    float2* Spair   = (float2*)(ws + 14942208);         //   393,216 B
    float2* Dpair   = (float2*)(ws + 15335424);         //   393,216 B
    u32*    maskbuf = (u32*)(ws + 15728640);            //   262,144 B

    prep_kernel<<<PACK_BLOCKS + CONV_BLOCKS, 256, 0, stream>>>(
        adj, feat, W, Hw, maskbuf, featb, Wt, Hwb);
    gemm_h_kernel<<<dim3(MM / 32, AH), 128, 0, stream>>>(
        featb, Wt, wsrc, wdst, hT, Spair, Dpair);
    attn_kernel<<<dim3(NN / 32, YY), 128, 0, stream>>>(
        hT, Spair, Dpair, maskbuf, bvec, featb, Hwb, Hb, feat, out);
}

// Round 15
// 122.813 us; speedup vs baseline: 1.0818x; 1.0818x over previous
//
#include <hip/hip_runtime.h>
#include <hip/hip_bf16.h>

#define BB 8
#define NN 512
#define AH 12
#define DIN 768
#define EE 64
#define MM (BB*NN)          // 4096
#define YY (BB*AH)          // 96
#define LEAKY 0.2f

typedef unsigned short u16;
typedef unsigned int u32;
typedef __attribute__((ext_vector_type(8))) short short8;
typedef __attribute__((ext_vector_type(4))) float f32x4;
typedef __attribute__((ext_vector_type(4))) u32 u32x4;

// float -> bf16 RNE
static __device__ __forceinline__ u16 f2bf(float f) {
    u32 u = __builtin_bit_cast(u32, f);
    u32 r = (u + 0x7FFFu + ((u >> 16) & 1u)) >> 16;
    return (u16)r;
}
static __device__ __forceinline__ u32 pk2(float a, float b) {
    return (u32)f2bf(a) | ((u32)f2bf(b) << 16);
}
// truncation pack (p >= 0): used only for P (rel err <= 2^-8)
static __device__ __forceinline__ u32 pk2t(float a, float b) {
    return (__builtin_bit_cast(u32, a) >> 16) | (__builtin_bit_cast(u32, b) & 0xFFFF0000u);
}
static __device__ __forceinline__ float ftanh(float x) {
    x = fminf(fmaxf(x, -15.f), 15.f);
    return 1.f - 2.f / (__expf(2.f * x) + 1.f);
}
static __device__ __forceinline__ float sigm(float z) {
    z = fminf(fmaxf(z, -80.f), 80.f);
    return 1.f / (1.f + __expf(-z));
}
// async global->LDS, 16B per lane
static __device__ __forceinline__ void gl_lds16(const u16* g, u16* l) {
    __builtin_amdgcn_global_load_lds((const __attribute__((address_space(1))) unsigned int*)g,
                                     (__attribute__((address_space(3))) unsigned int*)l,
                                     16, 0, 0);
}

// ---------------------------------------------------------------------------
// Hardware C/D-layout probe (validated rounds 6-14).
// ---------------------------------------------------------------------------
static __device__ __forceinline__ void mfma_probe(int lane, int* prow, int* pcol) {
    int q = lane >> 4, x = lane & 15;
    short8 af, bf;
#pragma unroll
    for (int j = 0; j < 8; j++) {
        int k = q * 8 + j;
        af[j] = (short)f2bf((k < 16) ? (float)(x * 16 + k) : 0.f);
        bf[j] = (short)f2bf((k == x) ? 1.f : 0.f);
    }
    f32x4 d = {};
    d = __builtin_amdgcn_mfma_f32_16x16x32_bf16(af, bf, d, 0, 0, 0);
#pragma unroll
    for (int r = 0; r < 4; r++) {
        int v = (int)(d[r] + 0.5f);
        prow[r] = v >> 4;
        pcol[r] = v & 15;
    }
}

// ---------------------------------------------------------------------------
// Prep: pack_adj (blocks 0..1023) + bf16 conversions (verified).
// ---------------------------------------------------------------------------
#define N_FEAT (MM*DIN)            // 3145728
#define N_W    (AH*DIN*EE)         // 589824
#define PACK_BLOCKS (MM/4)         // 1024
#define CONV_BLOCKS ((N_FEAT + 2*N_W)/256)  // 16896
__global__ __launch_bounds__(256) void prep_kernel(const int* __restrict__ adj,
                                                   const float* __restrict__ feat,
                                                   const float* __restrict__ W,
                                                   const float* __restrict__ Hw,
                                                   u32* __restrict__ maskbuf,
                                                   u16* __restrict__ featb,
                                                   u16* __restrict__ Wt,
                                                   u16* __restrict__ Hwb) {
    int blk = blockIdx.x, t = threadIdx.x;
    if (blk < PACK_BLOCKS) {
        int w = t >> 6, ln = t & 63;
        int row = blk * 4 + w;
        const int* ar = adj + (size_t)row * NN;
#pragma unroll
        for (int it = 0; it < 8; it++) {
            unsigned long long bal = __ballot(ar[it * 64 + ln] != 0);
            if (ln == 0) {
                maskbuf[row * 16 + it * 2]     = (u32)bal;
                maskbuf[row * 16 + it * 2 + 1] = (u32)(bal >> 32);
            }
        }
        return;
    }
    int i = (blk - PACK_BLOCKS) * 256 + t;
    if (i < N_FEAT) { featb[i] = f2bf(feat[i]); return; }
    int i2 = i - N_FEAT;
    if (i2 < N_W) {
        int a = i2 / (DIN * EE), rem = i2 % (DIN * EE);
        int e = rem / DIN, d = rem % DIN;
        Wt[i2] = f2bf(W[a * (DIN * EE) + d * EE + e]);
        return;
    }
    int i3 = i2 - N_W;
    Hwb[i3] = f2bf(Hw[i3]);
}

// ---------------------------------------------------------------------------
// Fused dual GEMM (h + gate): 64 nodes x (64 e  |  64 gate cols), 256 thr,
// grid (64, 12). One staged A tile feeds two B tiles (Wt head a, Hwb cols
// a*64..). Same verified staging/swizzle/fragment conventions as rounds 9-13.
// Epilogues: bf16 hT3 [y][kc][e][8] + factored exp pairs; sigmoid -> Gbuf.
// ---------------------------------------------------------------------------
__global__ __launch_bounds__(256) void gemm_fused_kernel(const u16* __restrict__ featb,
                                                         const u16* __restrict__ Wt,
                                                         const u16* __restrict__ Hwb,
                                                         const float* __restrict__ wsrc,
                                                         const float* __restrict__ wdst,
                                                         const float* __restrict__ Hb,
                                                         u16* __restrict__ hT,
                                                         float2* __restrict__ Spair,
                                                         float2* __restrict__ Dpair,
                                                         float* __restrict__ Gbuf) {
    __shared__ u16 As[64 * 64];
    __shared__ u16 BsW[64 * 64];
    __shared__ u16 BsG[64 * 64];
    __shared__ alignas(16) float cs[64][68];
    int t = threadIdx.x, w = t >> 6, lane = t & 63, q = lane >> 4, x = lane & 15;
    int m0 = blockIdx.x * 64, a = blockIdx.y;

    int wm = w & 1, wn = w >> 1, xr = x & 7;
    int srow = t >> 3;
    int skoff = ((t & 7) ^ (srow & 7)) * 8;
    const u16* Agp  = featb + (size_t)m0 * DIN + srow * DIN + skoff;
    const u16* BWgp = Wt + (size_t)a * EE * DIN + srow * DIN + skoff;
    const u16* BGgp = Hwb + (size_t)(a * EE) * DIN + srow * DIN + skoff;
    u16* Asw  = As  + w * 512;
    u16* BWsw = BsW + w * 512;
    u16* BGsw = BsG + w * 512;
    const u16* ApA  = As  + (wm * 32 + x) * 64;
    const u16* ApBW = BsW + (wn * 32 + x) * 64;
    const u16* ApBG = BsG + (wn * 32 + x) * 64;
    f32x4 aW00 = {}, aW01 = {}, aW10 = {}, aW11 = {};
    f32x4 aG00 = {}, aG01 = {}, aG10 = {}, aG11 = {};

    for (int k0 = 0; k0 < DIN; k0 += 64) {
        gl_lds16(Agp + k0, Asw);
        gl_lds16(Agp + 32 * DIN + k0, Asw + 2048);
        gl_lds16(BWgp + k0, BWsw);
        gl_lds16(BWgp + 32 * DIN + k0, BWsw + 2048);
        gl_lds16(BGgp + k0, BGsw);
        gl_lds16(BGgp + 32 * DIN + k0, BGsw + 2048);
        __syncthreads();
#pragma unroll
        for (int kk = 0; kk < 2; kk++) {
            int c8 = ((q + kk * 4) ^ xr) * 8;
            short8 a0 = *(const short8*)(ApA + c8);
            short8 a1 = *(const short8*)(ApA + 16 * 64 + c8);
            short8 bW0 = *(const short8*)(ApBW + c8);
            short8 bW1 = *(const short8*)(ApBW + 16 * 64 + c8);
            short8 bG0 = *(const short8*)(ApBG + c8);
            short8 bG1 = *(const short8*)(ApBG + 16 * 64 + c8);
            aW00 = __builtin_amdgcn_mfma_f32_16x16x32_bf16(a0, bW0, aW00, 0, 0, 0);
            aW01 = __builtin_amdgcn_mfma_f32_16x16x32_bf16(a0, bW1, aW01, 0, 0, 0);
            aW10 = __builtin_amdgcn_mfma_f32_16x16x32_bf16(a1, bW0, aW10, 0, 0, 0);
            aW11 = __builtin_amdgcn_mfma_f32_16x16x32_bf16(a1, bW1, aW11, 0, 0, 0);
            aG00 = __builtin_amdgcn_mfma_f32_16x16x32_bf16(a0, bG0, aG00, 0, 0, 0);
            aG01 = __builtin_amdgcn_mfma_f32_16x16x32_bf16(a0, bG1, aG01, 0, 0, 0);
            aG10 = __builtin_amdgcn_mfma_f32_16x16x32_bf16(a1, bG0, aG10, 0, 0, 0);
            aG11 = __builtin_amdgcn_mfma_f32_16x16x32_bf16(a1, bG1, aG11, 0, 0, 0);
        }
        __syncthreads();
    }

    int prow[4], pcol[4];
    mfma_probe(lane, prow, pcol);

    // ---- h: C -> LDS, then hT3 + factored exp pairs ----
#pragma unroll
    for (int r = 0; r < 4; r++) {
        cs[wm * 32 + prow[r]][wn * 32 + pcol[r]]           = aW00[r];
        cs[wm * 32 + prow[r]][wn * 32 + 16 + pcol[r]]      = aW01[r];
        cs[wm * 32 + 16 + prow[r]][wn * 32 + pcol[r]]      = aW10[r];
        cs[wm * 32 + 16 + prow[r]][wn * 32 + 16 + pcol[r]] = aW11[r];
    }
    __syncthreads();

    int b = m0 >> 9;
    int y = b * AH + a;
    int nbase = m0 & 511;
    {
        int kcb = nbase >> 3;
#pragma unroll
        for (int i = 0; i < 2; i++) {
            int idx = i * 256 + t;
            int kcl = idx >> 6, e = idx & 63;
            int r0 = kcl * 8;
            u32x4 wv = { pk2(cs[r0 + 0][e], cs[r0 + 1][e]),
                         pk2(cs[r0 + 2][e], cs[r0 + 3][e]),
                         pk2(cs[r0 + 4][e], cs[r0 + 5][e]),
                         pk2(cs[r0 + 6][e], cs[r0 + 7][e]) };
            *(u32x4*)&hT[((((size_t)y << 6) + kcb + kcl) << 6 | e) * 8] = wv;
        }
    }
    {
        int r = t >> 2, cg = t & 3;
        float s = 0.f, d = 0.f;
#pragma unroll
        for (int i = 0; i < 16; i++) {
            int e2 = cg * 16 + i;
            float th = ftanh(cs[r][e2]);
            s += th * wsrc[a * EE + e2];
            d += th * wdst[a * EE + e2];
        }
        s += __shfl_xor(s, 1); s += __shfl_xor(s, 2);
        d += __shfl_xor(d, 1); d += __shfl_xor(d, 2);
        if (cg == 0) {
            s = fminf(fmaxf(s, -40.f), 40.f);
            d = fminf(fmaxf(d, -40.f), 40.f);
            Spair[y * NN + nbase + r] = make_float2(__expf(s), __expf(0.2f * s));
            Dpair[y * NN + nbase + r] = make_float2(__expf(d), __expf(0.2f * d));
        }
    }
    __syncthreads();

    // ---- gate: C -> LDS, then sigmoid -> Gbuf ----
#pragma unroll
    for (int r = 0; r < 4; r++) {
        cs[wm * 32 + prow[r]][wn * 32 + pcol[r]]           = aG00[r];
        cs[wm * 32 + prow[r]][wn * 32 + 16 + pcol[r]]      = aG01[r];
        cs[wm * 32 + 16 + prow[r]][wn * 32 + pcol[r]]      = aG10[r];
        cs[wm * 32 + 16 + prow[r]][wn * 32 + 16 + pcol[r]] = aG11[r];
    }
    __syncthreads();

    {
        int n0 = a * EE;
        float4 hb = *(const float4*)&Hb[n0 + (t & 15) * 4];
#pragma unroll
        for (int p = 0; p < 4; p++) {
            int ml = p * 16 + (t >> 4), c4 = (t & 15) * 4;
            float4 v4 = *(const float4*)&cs[ml][c4];
            size_t idx = (size_t)(m0 + ml) * DIN + n0 + c4;
            float4 o;
            o.x = sigm(v4.x + hb.x);
            o.y = sigm(v4.y + hb.y);
            o.z = sigm(v4.z + hb.z);
            o.w = sigm(v4.w + hb.w);
            *(float4*)&Gbuf[idx] = o;
        }
    }
}

// ---------------------------------------------------------------------------
// Attention: pure PV via MFMA (factored exp, on-the-fly row sum, coalesced
// hT3 B-loads) + fused elu/gate-blend epilogue reading Gbuf. 256 thr,
// grid (8, 96). All components verified rounds 10-13.
// ---------------------------------------------------------------------------
__global__ __launch_bounds__(256) void attn_kernel(const u16* __restrict__ hT,
                                                   const float2* __restrict__ Spair,
                                                   const float2* __restrict__ Dpair,
                                                   const u32* __restrict__ maskbuf,
                                                   const float* __restrict__ bias,
                                                   const float* __restrict__ Gbuf,
                                                   const float* __restrict__ feat,
                                                   float* __restrict__ out) {
    __shared__ alignas(16) float2 sd2[NN];
    __shared__ u32 smask[64][17];
    __shared__ float silv[64];
    __shared__ alignas(16) float cs[64][68];

    int t = threadIdx.x;
    int y = blockIdx.y, bb = y / AH, a = y % AH;
    int i0 = blockIdx.x * 64;
    int w = t >> 6, lane = t & 63, q = lane >> 4, x = lane & 15;

    sd2[t] = Dpair[y * NN + t];
    sd2[t + 256] = Dpair[y * NN + 256 + t];
#pragma unroll
    for (int p = 0; p < 4; p++) {
        int idx = p * 256 + t, r = idx >> 4, c = idx & 15;
        smask[r][c] = maskbuf[((bb << 9) + i0 + r) * 16 + c];
    }
    __syncthreads();

    int rowl = w * 16 + x;
    float2 se = Spair[y * NN + i0 + rowl];
    float es1 = se.x, es2 = se.y;

    u32 anym = 0;
#pragma unroll
    for (int c = 0; c < 16; c++) anym |= smask[rowl][c];
    int uni = (anym == 0);

    const u16* hTy = hT + ((size_t)y << 12) * 8;     // y * 64 * 64 * 8
    f32x4 acc[4] = {};
    float lsum = 0.f;

#pragma unroll 2
    for (int k0 = 0; k0 < NN; k0 += 32) {
        u32 mb = smask[rowl][k0 >> 5] >> (q * 8);
        float pv[8];
#pragma unroll
        for (int j = 0; j < 8; j++) {
            float2 dp = sd2[k0 + q * 8 + j];
            float m1 = es1 * dp.x;
            float m2 = es2 * dp.y;
            float p = (m1 >= 1.f) ? m1 : m2;    // exp(leaky(s+d))
            p = ((mb >> j) & 1) ? p : 0.f;
            p = uni ? 1.0f : p;
            lsum += p;
            pv[j] = p;
        }
        short8 af = __builtin_bit_cast(short8, (u32x4){
            pk2t(pv[0], pv[1]), pk2t(pv[2], pv[3]),
            pk2t(pv[4], pv[5]), pk2t(pv[6], pv[7])});
        const u16* hp = hTy + ((((k0 >> 3) + q) << 6) + x) * 8;
        short8 b0 = *(const short8*)(hp);
        short8 b1 = *(const short8*)(hp + 16 * 8);
        short8 b2 = *(const short8*)(hp + 32 * 8);
        short8 b3 = *(const short8*)(hp + 48 * 8);
        acc[0] = __builtin_amdgcn_mfma_f32_16x16x32_bf16(af, b0, acc[0], 0, 0, 0);
        acc[1] = __builtin_amdgcn_mfma_f32_16x16x32_bf16(af, b1, acc[1], 0, 0, 0);
        acc[2] = __builtin_amdgcn_mfma_f32_16x16x32_bf16(af, b2, acc[2], 0, 0, 0);
        acc[3] = __builtin_amdgcn_mfma_f32_16x16x32_bf16(af, b3, acc[3], 0, 0, 0);
    }

    lsum += __shfl_xor(lsum, 16);
    lsum += __shfl_xor(lsum, 32);
    if (q == 0) silv[rowl] = 1.f / fmaxf(lsum, 1e-30f);

    int prow[4], pcol[4];
    mfma_probe(lane, prow, pcol);
#pragma unroll
    for (int nt = 0; nt < 4; nt++)
#pragma unroll
        for (int r = 0; r < 4; r++)
            cs[w * 16 + prow[r]][nt * 16 + pcol[r]] = acc[nt][r];
    __syncthreads();

    // ---- epilogue: normalize, +bias, elu, gate blend (Gbuf) ----
    float4 b4 = *(const float4*)&bias[(t & 15) * 4];
#pragma unroll
    for (int p = 0; p < 4; p++) {
        int nl = p * 16 + (t >> 4), e4 = (t & 15) * 4;
        float il = silv[nl];
        float4 c4 = *(const float4*)&cs[nl][e4];
        size_t base = ((size_t)(bb << 9) + i0 + nl) * DIN + a * EE + e4;
        float4 g4 = *(const float4*)&Gbuf[base];
        float4 f4 = *(const float4*)&feat[base];
        float4 o;
        float v, e;
        v = c4.x * il + b4.x; e = v > 0.f ? v : __expf(v) - 1.f; o.x = g4.x * e + (1.f - g4.x) * f4.x;
        v = c4.y * il + b4.y; e = v > 0.f ? v : __expf(v) - 1.f; o.y = g4.y * e + (1.f - g4.y) * f4.y;
        v = c4.z * il + b4.z; e = v > 0.f ? v : __expf(v) - 1.f; o.z = g4.z * e + (1.f - g4.z) * f4.z;
        v = c4.w * il + b4.w; e = v > 0.f ? v : __expf(v) - 1.f; o.w = g4.w * e + (1.f - g4.w) * f4.w;
        *(float4*)&out[base] = o;
    }
}

// ---------------------------------------------------------------------------
extern "C" void kernel_launch(void* const* d_in, const int* in_sizes, int n_in,
                              void* d_out, int out_size, void* d_ws, size_t ws_size,
                              hipStream_t stream) {
    const float* feat  = (const float*)d_in[0];
    const int*   adj   = (const int*)  d_in[1];
    const float* W     = (const float*)d_in[2];
    const float* bvec  = (const float*)d_in[3];
    const float* wsrc  = (const float*)d_in[4];
    const float* wdst  = (const float*)d_in[5];
    const float* Hw    = (const float*)d_in[6];
    const float* Hb    = (const float*)d_in[7];
    float* out = (float*)d_out;

    char* ws = (char*)d_ws;
    u16*    featb   = (u16*)(ws);                       // 6,291,456 B
    u16*    Wt      = (u16*)(ws + 6291456);             // 1,179,648 B
    u16*    Hwb     = (u16*)(ws + 7471104);             // 1,179,648 B
    u16*    hT      = (u16*)(ws + 8650752);             // 6,291,456 B
    float2* Spair   = (float2*)(ws + 14942208);         //   393,216 B
    float2* Dpair   = (float2*)(ws + 15335424);         //   393,216 B
    u32*    maskbuf = (u32*)(ws + 15728640);            //   262,144 B
    float*  Gbuf    = (float*)(ws + 15990784);          // 12,582,912 B

    prep_kernel<<<PACK_BLOCKS + CONV_BLOCKS, 256, 0, stream>>>(
        adj, feat, W, Hw, maskbuf, featb, Wt, Hwb);
    gemm_fused_kernel<<<dim3(MM / 64, AH), 256, 0, stream>>>(
        featb, Wt, Hwb, wsrc, wdst, Hb, hT, Spair, Dpair, Gbuf);
    attn_kernel<<<dim3(NN / 64, YY), 256, 0, stream>>>(
        hT, Spair, Dpair, maskbuf, bvec, Gbuf, feat, out);
}